// Round 5
// baseline (183.341 us; speedup 1.0000x reference)
//
#include <hip/hip_runtime.h>
#include <math.h>

#define AB 128   // A == B == 128
#define NN 64    // N
#define HD 1024  // H

// fp32 -> f16 hi/lo split scales. Z ~ N(0,1) -> x256 keeps lo normal;
// F entries ~1e-2 -> x64. out = acc * gamma * 2^-20.
#define SFZ 256.0f
#define SFF 64.0f
#define DESCALE (1.0f / 1048576.0f)  // 2^-(8+6+6)

typedef _Float16 half8 __attribute__((ext_vector_type(8)));
typedef float f32x4 __attribute__((ext_vector_type(4)));
typedef unsigned u32x4 __attribute__((ext_vector_type(4)));

// ---------------------------------------------------------------------------
// ws layout (halfs):
//   [0,     8192)   FXhi K-major plane: addr = (b>>3)*512 + m*8 + (b&7)
//   [8192,  16384)  FXlo K-major plane (same addressing)
//   [16384, 24576)  FYhi[n][a] row-major
//   [24576, 32768)  FYlo[n][a] row-major
//   float at float-index 16384 (byte 65536): gamma * 2^-20
// K-major plane: granule (8 halfs) per (row, a-block); fragment reads are
// contiguous half8 -> direct ds_read_b128 feeding MFMA, no unpacking.
// ---------------------------------------------------------------------------

__device__ __forceinline__ float wave_reduce(float v) {
  v += __shfl_down(v, 32);
  v += __shfl_down(v, 16);
  v += __shfl_down(v, 8);
  v += __shfl_down(v, 4);
  v += __shfl_down(v, 2);
  v += __shfl_down(v, 1);
  return v;  // valid in lane 0
}

__global__ __launch_bounds__(1024) void fb_setup(
    const float* __restrict__ h, const float* __restrict__ Ww,
    const float* __restrict__ Wb, void* __restrict__ wsv) {
  __shared__ float redp[16][5];
  __shared__ float reds[16][2];
  __shared__ float sc[5];
  __shared__ float ssum[2];
  const int tid = threadIdx.x;
  const int lane = tid & 63;
  const int wv = tid >> 6;

  const float hv = h[tid];
  float p[5];
#pragma unroll
  for (int j = 0; j < 5; ++j) p[j] = hv * Ww[j * HD + tid];
#pragma unroll
  for (int j = 0; j < 5; ++j) {
    float r = wave_reduce(p[j]);
    if (lane == 0) redp[wv][j] = r;
  }
  __syncthreads();
  if (tid < 5) {
    float s = Wb[tid];
#pragma unroll
    for (int w = 0; w < 16; ++w) s += redp[w][tid];
    sc[tid] = s;
  }
  __syncthreads();

  const float gt_X = sc[0], gt_Y = sc[1], log_var = sc[2], log_dt = sc[3];
  const float var = expf(log_var + 1e-8f);
  const float g_X = (129.0f * (gt_X + 1.0f)) / 2.0f;
  const float g_Y = (129.0f * (gt_Y + 1.0f)) / 2.0f;
  const float d = (expf(log_dt) * 127.0f) / 63.0f;
  const float twovar = 2.0f * var;

  float fyv[8], fxv[8];
  float sY = 0.f, sX = 0.f;
#pragma unroll
  for (int c = 0; c < 8; ++c) {
    const int idx = tid + 1024 * c;
    const int n = idx >> 7;
    const int col = idx & 127;
    const float idxn = (float)n - 32.5f;
    const float muX = g_X + idxn * d;
    const float muY = g_Y + idxn * d;
    const float dx = (float)col - muX;
    const float dy = (float)col - muY;
    const float fx = expf(-(dx * dx) / twovar);
    const float fy = expf(-(dy * dy) / twovar);
    fyv[c] = fy;
    fxv[c] = fx;
    sY += fy;
    sX += fx;
  }
  {
    float rY = wave_reduce(sY);
    float rX = wave_reduce(sX);
    if (lane == 0) { reds[wv][0] = rY; reds[wv][1] = rX; }
  }
  __syncthreads();
  if (tid < 2) {
    float s = 0.f;
#pragma unroll
    for (int w = 0; w < 16; ++w) s += reds[w][tid];
    ssum[tid] = s;
  }
  __syncthreads();
  const float invY = 1.0f / ssum[0];
  const float invX = 1.0f / ssum[1];

  _Float16* FXk = (_Float16*)wsv;                 // hi plane; lo at +8192
  _Float16* FYhi = (_Float16*)wsv + 2 * NN * AB;  // half 16384
  _Float16* FYlo = FYhi + NN * AB;                // half 24576

#pragma unroll
  for (int c = 0; c < 8; ++c) {
    const int idx = tid + 1024 * c;  // n*128 + col
    const int n = idx >> 7;
    const int col = idx & 127;
    const float vy = fyv[c] * invY * SFF;
    const float vx = fxv[c] * invX * SFF;
    const _Float16 yh = (_Float16)vy;
    const _Float16 xh2 = (_Float16)vx;
    FYhi[idx] = yh;
    FYlo[idx] = (_Float16)(vy - (float)yh);
    const int kaddr = ((col >> 3) << 9) + (n << 3) + (col & 7);
    FXk[kaddr] = xh2;
    FXk[8192 + kaddr] = (_Float16)(vx - (float)xh2);
  }
  if (tid == 0) ((float*)wsv)[16384] = expf(sc[4]) * DESCALE;
}

// ---------------------------------------------------------------------------
// fb_filt: one block (256 thr = 4 waves) per image half; 5 blocks/CU.
// Phase 0: Z ks01 into regs; linear 32 KB copy of FX hi/lo K-major planes
//          into LDS; barrier 1.
// Stage 1: Z ks23 issued (pinned); per ks: split Z in regs; A-frags are
//          direct half8 ds_read_b128 (K-major, no unpack); 24 MFMAs/ks.
//          Barrier 2.
// S' -> same LDS planes via b16 stores (hi+lo), K-major. FY frags (8 half8)
//          prefetched from global. Barrier 3.
// Stage 2: B-frags direct half8 ds_reads; 12 MFMAs/ks; FY from regs.
// 3-product f16 emulation: Ahi*Bhi + Ahi*Blo + Alo*Bhi (fp32 acc).
// ---------------------------------------------------------------------------
__device__ __forceinline__ void split8(const f32x4 z0, const f32x4 z1,
                                       float s, half8& hi, half8& lo) {
#pragma unroll
  for (int e = 0; e < 8; ++e) {
    const float q = (e < 4 ? z0[e] : z1[e - 4]) * s;
    const _Float16 hh = (_Float16)q;
    hi[e] = hh;
    lo[e] = (_Float16)(q - (float)hh);
  }
}

__global__ __launch_bounds__(256, 5) void fb_filt(
    const float* __restrict__ x, const float* __restrict__ xh,
    const void* __restrict__ wsv, float* __restrict__ out) {
  __shared__ __align__(16) _Float16 S_lds[2 * NN * AB];  // 32 KB: FX, then S'

  const int tid = threadIdx.x;
  const int lane = tid & 63;
  const int wv = tid >> 6;   // 0..3
  const int l15 = lane & 15;
  const int h4 = lane >> 4;  // 0..3
  const int bid = blockIdx.x;
  const int img = bid >> 1;
  const int which = bid & 1;
  const float* __restrict__ Z = (which ? xh : x) + (size_t)img * (AB * AB);
  const _Float16* __restrict__ FYhi = (const _Float16*)wsv + 2 * NN * AB;
  const _Float16* __restrict__ FYlo = FYhi + NN * AB;
  const float gamma_eff = ((const float*)wsv)[16384];

  // ---- Phase 0: Z ks01 batch + linear FX plane copy ----
  const float* __restrict__ zrow = Z + (32 * wv + l15) * AB + 8 * h4;
  f32x4 z[4][4];
#pragma unroll
  for (int ks = 0; ks < 2; ++ks) {
    const float* p0 = zrow + 32 * ks;
    const float* p1 = zrow + 16 * AB + 32 * ks;
    z[ks][0] = *(const f32x4*)p0;
    z[ks][1] = *(const f32x4*)(p0 + 4);
    z[ks][2] = *(const f32x4*)p1;
    z[ks][3] = *(const f32x4*)(p1 + 4);
  }
  {
    const u32x4* __restrict__ src = (const u32x4*)wsv;  // 2048 granules
    u32x4* __restrict__ dst = (u32x4*)S_lds;
#pragma unroll
    for (int c = 0; c < 8; ++c) dst[c * 256 + tid] = src[c * 256 + tid];
  }
  __syncthreads();  // barrier 1: FX planes resident

  // ---- issue Z ks23, pinned ahead of stage-1 compute ----
#pragma unroll
  for (int ks = 2; ks < 4; ++ks) {
    const float* p0 = zrow + 32 * ks;
    const float* p1 = zrow + 16 * AB + 32 * ks;
    z[ks][0] = *(const f32x4*)p0;
    z[ks][1] = *(const f32x4*)(p0 + 4);
    z[ks][2] = *(const f32x4*)p1;
    z[ks][3] = *(const f32x4*)(p1 + 4);
  }
  __builtin_amdgcn_sched_barrier(0);

  // ---- Stage 1: S'(64x128) = FXs @ Zs^T ----
  f32x4 acc[4][2];
#pragma unroll
  for (int mt = 0; mt < 4; ++mt)
#pragma unroll
    for (int j = 0; j < 2; ++j) acc[mt][j] = {0.f, 0.f, 0.f, 0.f};

#pragma unroll
  for (int ks = 0; ks < 4; ++ks) {
    half8 bhi[2], blo[2];
    split8(z[ks][0], z[ks][1], SFZ, bhi[0], blo[0]);
    split8(z[ks][2], z[ks][3], SFZ, bhi[1], blo[1]);
    const int gbase = ((4 * ks + h4) << 9);
#pragma unroll
    for (int mt = 0; mt < 4; ++mt) {
      const _Float16* ap = S_lds + gbase + ((16 * mt + l15) << 3);
      const half8 ahi = *(const half8*)ap;
      const half8 alo = *(const half8*)(ap + 8192);
#pragma unroll
      for (int j = 0; j < 2; ++j) {
        acc[mt][j] = __builtin_amdgcn_mfma_f32_16x16x32_f16(ahi, bhi[j], acc[mt][j], 0, 0, 0);
        acc[mt][j] = __builtin_amdgcn_mfma_f32_16x16x32_f16(ahi, blo[j], acc[mt][j], 0, 0, 0);
        acc[mt][j] = __builtin_amdgcn_mfma_f32_16x16x32_f16(alo, bhi[j], acc[mt][j], 0, 0, 0);
      }
    }
  }
  __syncthreads();  // barrier 2: all FX reads complete before overwrite

  // ---- S' -> LDS planes (hi, lo) via b16 stores, K-major ----
#pragma unroll
  for (int mt = 0; mt < 4; ++mt) {
#pragma unroll
    for (int j = 0; j < 2; ++j) {
      // a = 32wv + 16j + l15 -> granule 4wv+2j+(l15>>3), elem l15&7
      const int abase = ((4 * wv + 2 * j + (l15 >> 3)) << 9) + (l15 & 7);
#pragma unroll
      for (int r = 0; r < 4; ++r) {
        const int row = 16 * mt + 4 * h4 + r;
        const float v = acc[mt][j][r];
        const _Float16 hh = (_Float16)v;
        const _Float16 ll = (_Float16)(v - (float)hh);
        S_lds[abase + (row << 3)] = hh;
        S_lds[8192 + abase + (row << 3)] = ll;
      }
    }
  }

  // ---- prefetch FY frags (global) so they fly across barrier 3 ----
  half8 fyh[4], fyl[4];
#pragma unroll
  for (int ks = 0; ks < 4; ++ks) {
    const int foff = (16 * wv + l15) * AB + 32 * ks + 8 * h4;
    fyh[ks] = *(const half8*)(FYhi + foff);
    fyl[ks] = *(const half8*)(FYlo + foff);
  }
  __builtin_amdgcn_sched_barrier(0);
  __syncthreads();  // barrier 3: S' resident

  // ---- Stage 2: out(64x64) = FYs @ S'^T ----
  f32x4 acc2[4];
#pragma unroll
  for (int mt = 0; mt < 4; ++mt) acc2[mt] = {0.f, 0.f, 0.f, 0.f};

#pragma unroll
  for (int ks = 0; ks < 4; ++ks) {
    const int gbase = ((4 * ks + h4) << 9);
#pragma unroll
    for (int mt = 0; mt < 4; ++mt) {
      const _Float16* bp = S_lds + gbase + ((16 * mt + l15) << 3);
      const half8 bh = *(const half8*)bp;
      const half8 bl = *(const half8*)(bp + 8192);
      acc2[mt] = __builtin_amdgcn_mfma_f32_16x16x32_f16(fyh[ks], bh, acc2[mt], 0, 0, 0);
      acc2[mt] = __builtin_amdgcn_mfma_f32_16x16x32_f16(fyh[ks], bl, acc2[mt], 0, 0, 0);
      acc2[mt] = __builtin_amdgcn_mfma_f32_16x16x32_f16(fyl[ks], bh, acc2[mt], 0, 0, 0);
    }
  }

  // ---- Epilogue: D[row = n = 16wv+4h4+r][col = m = 16mt+l15] ----
  float* __restrict__ ob = out + (size_t)img * 8192 + which * 4096;
#pragma unroll
  for (int mt = 0; mt < 4; ++mt) {
#pragma unroll
    for (int r = 0; r < 4; ++r) {
      ob[(16 * wv + 4 * h4 + r) * 64 + 16 * mt + l15] = acc2[mt][r] * gamma_eff;
    }
  }
}

extern "C" void kernel_launch(void* const* d_in, const int* in_sizes, int n_in,
                              void* d_out, int out_size, void* d_ws, size_t ws_size,
                              hipStream_t stream) {
  const float* x = (const float*)d_in[0];
  const float* xh = (const float*)d_in[1];
  const float* h = (const float*)d_in[2];
  const float* Ww = (const float*)d_in[3];
  const float* Wb = (const float*)d_in[4];
  float* outp = (float*)d_out;

  fb_setup<<<1, 1024, 0, stream>>>(h, Ww, Wb, d_ws);
  fb_filt<<<2048, 256, 0, stream>>>(x, xh, (const void*)d_ws, outp);
}

// Round 6
// 178.848 us; speedup vs baseline: 1.0251x; 1.0251x over previous
//
#include <hip/hip_runtime.h>
#include <math.h>

#define AB 128   // A == B == 128
#define NN 64    // N
#define HD 1024  // H

// fp32 -> f16 hi/lo split scales. Z ~ N(0,1) -> x256 keeps lo normal;
// F entries ~1e-2 -> x64. out = acc * gamma * 2^-20.
#define SFZ 256.0f
#define SFF 64.0f
#define DESCALE (1.0f / 1048576.0f)  // 2^-(8+6+6)

typedef _Float16 half8 __attribute__((ext_vector_type(8)));
typedef float f32x4 __attribute__((ext_vector_type(4)));
typedef unsigned u32x4 __attribute__((ext_vector_type(4)));

// ---------------------------------------------------------------------------
// ws layout (halfs):
//   [0,     8192)   FXhi K-major plane: addr = (b>>3)*512 + m*8 + (b&7)
//   [8192,  16384)  FXlo K-major plane (same addressing)
//   [16384, 24576)  FYhi[n][a] row-major
//   [24576, 32768)  FYlo[n][a] row-major
//   float at float-index 16384 (byte 65536): gamma * 2^-20
// ---------------------------------------------------------------------------

__device__ __forceinline__ float wave_reduce(float v) {
  v += __shfl_down(v, 32);
  v += __shfl_down(v, 16);
  v += __shfl_down(v, 8);
  v += __shfl_down(v, 4);
  v += __shfl_down(v, 2);
  v += __shfl_down(v, 1);
  return v;  // valid in lane 0
}

__global__ __launch_bounds__(1024) void fb_setup(
    const float* __restrict__ h, const float* __restrict__ Ww,
    const float* __restrict__ Wb, void* __restrict__ wsv) {
  __shared__ float redp[16][5];
  __shared__ float reds[16][2];
  __shared__ float sc[5];
  __shared__ float ssum[2];
  const int tid = threadIdx.x;
  const int lane = tid & 63;
  const int wv = tid >> 6;

  const float hv = h[tid];
  float p[5];
#pragma unroll
  for (int j = 0; j < 5; ++j) p[j] = hv * Ww[j * HD + tid];
#pragma unroll
  for (int j = 0; j < 5; ++j) {
    float r = wave_reduce(p[j]);
    if (lane == 0) redp[wv][j] = r;
  }
  __syncthreads();
  if (tid < 5) {
    float s = Wb[tid];
#pragma unroll
    for (int w = 0; w < 16; ++w) s += redp[w][tid];
    sc[tid] = s;
  }
  __syncthreads();

  const float gt_X = sc[0], gt_Y = sc[1], log_var = sc[2], log_dt = sc[3];
  const float var = expf(log_var + 1e-8f);
  const float g_X = (129.0f * (gt_X + 1.0f)) / 2.0f;
  const float g_Y = (129.0f * (gt_Y + 1.0f)) / 2.0f;
  const float d = (expf(log_dt) * 127.0f) / 63.0f;
  const float twovar = 2.0f * var;

  float fyv[8], fxv[8];
  float sY = 0.f, sX = 0.f;
#pragma unroll
  for (int c = 0; c < 8; ++c) {
    const int idx = tid + 1024 * c;
    const int n = idx >> 7;
    const int col = idx & 127;
    const float idxn = (float)n - 32.5f;
    const float muX = g_X + idxn * d;
    const float muY = g_Y + idxn * d;
    const float dx = (float)col - muX;
    const float dy = (float)col - muY;
    const float fx = expf(-(dx * dx) / twovar);
    const float fy = expf(-(dy * dy) / twovar);
    fyv[c] = fy;
    fxv[c] = fx;
    sY += fy;
    sX += fx;
  }
  {
    float rY = wave_reduce(sY);
    float rX = wave_reduce(sX);
    if (lane == 0) { reds[wv][0] = rY; reds[wv][1] = rX; }
  }
  __syncthreads();
  if (tid < 2) {
    float s = 0.f;
#pragma unroll
    for (int w = 0; w < 16; ++w) s += reds[w][tid];
    ssum[tid] = s;
  }
  __syncthreads();
  const float invY = 1.0f / ssum[0];
  const float invX = 1.0f / ssum[1];

  _Float16* FXk = (_Float16*)wsv;                 // hi plane; lo at +8192
  _Float16* FYhi = (_Float16*)wsv + 2 * NN * AB;  // half 16384
  _Float16* FYlo = FYhi + NN * AB;                // half 24576

#pragma unroll
  for (int c = 0; c < 8; ++c) {
    const int idx = tid + 1024 * c;  // n*128 + col
    const int n = idx >> 7;
    const int col = idx & 127;
    const float vy = fyv[c] * invY * SFF;
    const float vx = fxv[c] * invX * SFF;
    const _Float16 yh = (_Float16)vy;
    const _Float16 xh2 = (_Float16)vx;
    FYhi[idx] = yh;
    FYlo[idx] = (_Float16)(vy - (float)yh);
    const int kaddr = ((col >> 3) << 9) + (n << 3) + (col & 7);
    FXk[kaddr] = xh2;
    FXk[8192 + kaddr] = (_Float16)(vx - (float)xh2);
  }
  if (tid == 0) ((float*)wsv)[16384] = expf(sc[4]) * DESCALE;
}

// ---------------------------------------------------------------------------
// fb_filt: one block (256 thr = 4 waves) per image half; 4 blocks/CU.
// Phase 0: linear 32 KB copy of FX hi/lo K-major planes into LDS; barrier 1.
// Then: 16 inline-asm volatile global_load_dwordx4 for the whole Z strip
//   (2 base pointers + offset: immediates) -- compiler cannot sink these.
// Stage 1: per ks: s_waitcnt vmcnt(12/8/4/0) + sched_barrier(0), split Z,
//   A-frags via direct half8 ds_read (K-major, no unpack), 24 MFMAs.
//   Barrier 2.
// FY frags prefetched (normal loads; all asm loads drained -> compiler
//   vmcnt accounting stays valid). S' -> same LDS planes via b16 stores.
//   Barrier 3.
// Stage 2: B-frags direct half8 ds_reads; 12 MFMAs/ks; FY from regs.
// 3-product f16 emulation: Ahi*Bhi + Ahi*Blo + Alo*Bhi (fp32 acc).
// ---------------------------------------------------------------------------
__device__ __forceinline__ void split8(const f32x4 z0, const f32x4 z1,
                                       float s, half8& hi, half8& lo) {
#pragma unroll
  for (int e = 0; e < 8; ++e) {
    const float q = (e < 4 ? z0[e] : z1[e - 4]) * s;
    const _Float16 hh = (_Float16)q;
    hi[e] = hh;
    lo[e] = (_Float16)(q - (float)hh);
  }
}

#define ZLD(dst, base, OFF)                                              \
  asm volatile("global_load_dwordx4 %0, %1, off offset:" #OFF            \
               : "=v"(dst) : "v"(base))

#define WAITVM_SB(N)                                                     \
  do {                                                                   \
    asm volatile("s_waitcnt vmcnt(" #N ")");                             \
    __builtin_amdgcn_sched_barrier(0);                                   \
  } while (0)

__global__ __launch_bounds__(256, 4) void fb_filt(
    const float* __restrict__ x, const float* __restrict__ xh,
    const void* __restrict__ wsv, float* __restrict__ out) {
  __shared__ __align__(16) _Float16 S_lds[2 * NN * AB];  // 32 KB: FX, then S'

  const int tid = threadIdx.x;
  const int lane = tid & 63;
  const int wv = tid >> 6;   // 0..3
  const int l15 = lane & 15;
  const int h4 = lane >> 4;  // 0..3
  const int bid = blockIdx.x;
  const int img = bid >> 1;
  const int which = bid & 1;
  const float* __restrict__ Z = (which ? xh : x) + (size_t)img * (AB * AB);
  const _Float16* __restrict__ FYhi = (const _Float16*)wsv + 2 * NN * AB;
  const _Float16* __restrict__ FYlo = FYhi + NN * AB;
  const float gamma_eff = ((const float*)wsv)[16384];

  // ---- Phase 0: linear FX plane copy (normal loads; drain at barrier) ----
  {
    const u32x4* __restrict__ src = (const u32x4*)wsv;  // 2048 granules
    u32x4* __restrict__ dst = (u32x4*)S_lds;
#pragma unroll
    for (int c = 0; c < 8; ++c) dst[c * 256 + tid] = src[c * 256 + tid];
  }
  __syncthreads();  // barrier 1: FX planes resident; vmcnt drained to 0

  // ---- Issue the entire Z strip: 16 volatile asm loads, in ks order ----
  const float* zb0 = Z + (32 * wv + l15) * AB + 8 * h4;  // j=0 rows
  const float* zb1 = zb0 + 16 * AB;                      // j=1 rows (+8192B)
  f32x4 z0_0, z0_1, z0_2, z0_3, z1_0, z1_1, z1_2, z1_3;
  f32x4 z2_0, z2_1, z2_2, z2_3, z3_0, z3_1, z3_2, z3_3;
  ZLD(z0_0, zb0, 0);   ZLD(z0_1, zb0, 16);
  ZLD(z0_2, zb1, 0);   ZLD(z0_3, zb1, 16);
  ZLD(z1_0, zb0, 128); ZLD(z1_1, zb0, 144);
  ZLD(z1_2, zb1, 128); ZLD(z1_3, zb1, 144);
  ZLD(z2_0, zb0, 256); ZLD(z2_1, zb0, 272);
  ZLD(z2_2, zb1, 256); ZLD(z2_3, zb1, 272);
  ZLD(z3_0, zb0, 384); ZLD(z3_1, zb0, 400);
  ZLD(z3_2, zb1, 384); ZLD(z3_3, zb1, 400);

  // ---- Stage 1: S'(64x128) = FXs @ Zs^T ----
  f32x4 acc[4][2];
#pragma unroll
  for (int mt = 0; mt < 4; ++mt)
#pragma unroll
    for (int j = 0; j < 2; ++j) acc[mt][j] = {0.f, 0.f, 0.f, 0.f};

#define S1_KS(KS, WN)                                                          \
  do {                                                                         \
    WAITVM_SB(WN);                                                             \
    half8 bhi0, blo0, bhi1, blo1;                                              \
    split8(z##KS##_0, z##KS##_1, SFZ, bhi0, blo0);                             \
    split8(z##KS##_2, z##KS##_3, SFZ, bhi1, blo1);                             \
    const int gbase = ((4 * (KS) + h4) << 9);                                  \
    _Pragma("unroll")                                                          \
    for (int mt = 0; mt < 4; ++mt) {                                           \
      const _Float16* ap = S_lds + gbase + ((16 * mt + l15) << 3);             \
      const half8 ahi = *(const half8*)ap;                                     \
      const half8 alo = *(const half8*)(ap + 8192);                            \
      acc[mt][0] = __builtin_amdgcn_mfma_f32_16x16x32_f16(ahi, bhi0, acc[mt][0], 0, 0, 0); \
      acc[mt][0] = __builtin_amdgcn_mfma_f32_16x16x32_f16(ahi, blo0, acc[mt][0], 0, 0, 0); \
      acc[mt][0] = __builtin_amdgcn_mfma_f32_16x16x32_f16(alo, bhi0, acc[mt][0], 0, 0, 0); \
      acc[mt][1] = __builtin_amdgcn_mfma_f32_16x16x32_f16(ahi, bhi1, acc[mt][1], 0, 0, 0); \
      acc[mt][1] = __builtin_amdgcn_mfma_f32_16x16x32_f16(ahi, blo1, acc[mt][1], 0, 0, 0); \
      acc[mt][1] = __builtin_amdgcn_mfma_f32_16x16x32_f16(alo, bhi1, acc[mt][1], 0, 0, 0); \
    }                                                                          \
  } while (0)

  S1_KS(0, 12);
  S1_KS(1, 8);
  S1_KS(2, 4);
  S1_KS(3, 0);
#undef S1_KS

  __syncthreads();  // barrier 2: all FX reads complete before overwrite

  // ---- prefetch FY frags (normal loads; asm loads are fully drained) ----
  half8 fyh[4], fyl[4];
#pragma unroll
  for (int ks = 0; ks < 4; ++ks) {
    const int foff = (16 * wv + l15) * AB + 32 * ks + 8 * h4;
    fyh[ks] = *(const half8*)(FYhi + foff);
    fyl[ks] = *(const half8*)(FYlo + foff);
  }

  // ---- S' -> LDS planes (hi, lo) via b16 stores, K-major ----
#pragma unroll
  for (int mt = 0; mt < 4; ++mt) {
#pragma unroll
    for (int j = 0; j < 2; ++j) {
      // a = 32wv + 16j + l15 -> granule 4wv+2j+(l15>>3), elem l15&7
      const int abase = ((4 * wv + 2 * j + (l15 >> 3)) << 9) + (l15 & 7);
#pragma unroll
      for (int r = 0; r < 4; ++r) {
        const int row = 16 * mt + 4 * h4 + r;
        const float v = acc[mt][j][r];
        const _Float16 hh = (_Float16)v;
        const _Float16 ll = (_Float16)(v - (float)hh);
        S_lds[abase + (row << 3)] = hh;
        S_lds[8192 + abase + (row << 3)] = ll;
      }
    }
  }
  __syncthreads();  // barrier 3: S' resident

  // ---- Stage 2: out(64x64) = FYs @ S'^T ----
  f32x4 acc2[4];
#pragma unroll
  for (int mt = 0; mt < 4; ++mt) acc2[mt] = {0.f, 0.f, 0.f, 0.f};

#pragma unroll
  for (int ks = 0; ks < 4; ++ks) {
    const int gbase = ((4 * ks + h4) << 9);
#pragma unroll
    for (int mt = 0; mt < 4; ++mt) {
      const _Float16* bp = S_lds + gbase + ((16 * mt + l15) << 3);
      const half8 bh = *(const half8*)bp;
      const half8 bl = *(const half8*)(bp + 8192);
      acc2[mt] = __builtin_amdgcn_mfma_f32_16x16x32_f16(fyh[ks], bh, acc2[mt], 0, 0, 0);
      acc2[mt] = __builtin_amdgcn_mfma_f32_16x16x32_f16(fyh[ks], bl, acc2[mt], 0, 0, 0);
      acc2[mt] = __builtin_amdgcn_mfma_f32_16x16x32_f16(fyl[ks], bh, acc2[mt], 0, 0, 0);
    }
  }

  // ---- Epilogue: D[row = n = 16wv+4h4+r][col = m = 16mt+l15] ----
  float* __restrict__ ob = out + (size_t)img * 8192 + which * 4096;
#pragma unroll
  for (int mt = 0; mt < 4; ++mt) {
#pragma unroll
    for (int r = 0; r < 4; ++r) {
      ob[(16 * wv + 4 * h4 + r) * 64 + 16 * mt + l15] = acc2[mt][r] * gamma_eff;
    }
  }
}

extern "C" void kernel_launch(void* const* d_in, const int* in_sizes, int n_in,
                              void* d_out, int out_size, void* d_ws, size_t ws_size,
                              hipStream_t stream) {
  const float* x = (const float*)d_in[0];
  const float* xh = (const float*)d_in[1];
  const float* h = (const float*)d_in[2];
  const float* Ww = (const float*)d_in[3];
  const float* Wb = (const float*)d_in[4];
  float* outp = (float*)d_out;

  fb_setup<<<1, 1024, 0, stream>>>(h, Ww, Wb, d_ws);
  fb_filt<<<2048, 256, 0, stream>>>(x, xh, (const void*)d_ws, outp);
}

// Round 7
// 177.431 us; speedup vs baseline: 1.0333x; 1.0080x over previous
//
#include <hip/hip_runtime.h>
#include <math.h>

#define AB 128   // A == B == 128
#define NN 64    // N
#define HD 1024  // H

// fp32 -> f16 hi/lo split scales. Z ~ N(0,1) -> x256 keeps lo normal;
// F entries ~1e-2 -> x64. out = acc * gamma * 2^-20.
#define SFZ 256.0f
#define SFF 64.0f
#define DESCALE (1.0f / 1048576.0f)  // 2^-(8+6+6)

typedef _Float16 half8 __attribute__((ext_vector_type(8)));
typedef float f32x4 __attribute__((ext_vector_type(4)));
typedef unsigned u32x4 __attribute__((ext_vector_type(4)));

// ---------------------------------------------------------------------------
// ws layout (halfs):
//   [0,     8192)   FXhi K-major plane: addr = (b>>3)*512 + m*8 + (b&7)
//   [8192,  16384)  FXlo K-major plane (same addressing)
//   [16384, 24576)  FYhi[n][a] row-major
//   [24576, 32768)  FYlo[n][a] row-major
//   float at float-index 16384 (byte 65536): gamma * 2^-20
// ---------------------------------------------------------------------------

__device__ __forceinline__ float wave_reduce(float v) {
  v += __shfl_down(v, 32);
  v += __shfl_down(v, 16);
  v += __shfl_down(v, 8);
  v += __shfl_down(v, 4);
  v += __shfl_down(v, 2);
  v += __shfl_down(v, 1);
  return v;  // valid in lane 0
}

__global__ __launch_bounds__(1024) void fb_setup(
    const float* __restrict__ h, const float* __restrict__ Ww,
    const float* __restrict__ Wb, void* __restrict__ wsv) {
  __shared__ float redp[16][5];
  __shared__ float reds[16][2];
  __shared__ float sc[5];
  __shared__ float ssum[2];
  const int tid = threadIdx.x;
  const int lane = tid & 63;
  const int wv = tid >> 6;

  const float hv = h[tid];
  float p[5];
#pragma unroll
  for (int j = 0; j < 5; ++j) p[j] = hv * Ww[j * HD + tid];
#pragma unroll
  for (int j = 0; j < 5; ++j) {
    float r = wave_reduce(p[j]);
    if (lane == 0) redp[wv][j] = r;
  }
  __syncthreads();
  if (tid < 5) {
    float s = Wb[tid];
#pragma unroll
    for (int w = 0; w < 16; ++w) s += redp[w][tid];
    sc[tid] = s;
  }
  __syncthreads();

  const float gt_X = sc[0], gt_Y = sc[1], log_var = sc[2], log_dt = sc[3];
  const float var = expf(log_var + 1e-8f);
  const float g_X = (129.0f * (gt_X + 1.0f)) / 2.0f;
  const float g_Y = (129.0f * (gt_Y + 1.0f)) / 2.0f;
  const float d = (expf(log_dt) * 127.0f) / 63.0f;
  const float twovar = 2.0f * var;

  float fyv[8], fxv[8];
  float sY = 0.f, sX = 0.f;
#pragma unroll
  for (int c = 0; c < 8; ++c) {
    const int idx = tid + 1024 * c;
    const int n = idx >> 7;
    const int col = idx & 127;
    const float idxn = (float)n - 32.5f;
    const float muX = g_X + idxn * d;
    const float muY = g_Y + idxn * d;
    const float dx = (float)col - muX;
    const float dy = (float)col - muY;
    const float fx = expf(-(dx * dx) / twovar);
    const float fy = expf(-(dy * dy) / twovar);
    fyv[c] = fy;
    fxv[c] = fx;
    sY += fy;
    sX += fx;
  }
  {
    float rY = wave_reduce(sY);
    float rX = wave_reduce(sX);
    if (lane == 0) { reds[wv][0] = rY; reds[wv][1] = rX; }
  }
  __syncthreads();
  if (tid < 2) {
    float s = 0.f;
#pragma unroll
    for (int w = 0; w < 16; ++w) s += reds[w][tid];
    ssum[tid] = s;
  }
  __syncthreads();
  const float invY = 1.0f / ssum[0];
  const float invX = 1.0f / ssum[1];

  _Float16* FXk = (_Float16*)wsv;                 // hi plane; lo at +8192
  _Float16* FYhi = (_Float16*)wsv + 2 * NN * AB;  // half 16384
  _Float16* FYlo = FYhi + NN * AB;                // half 24576

#pragma unroll
  for (int c = 0; c < 8; ++c) {
    const int idx = tid + 1024 * c;  // n*128 + col
    const int n = idx >> 7;
    const int col = idx & 127;
    const float vy = fyv[c] * invY * SFF;
    const float vx = fxv[c] * invX * SFF;
    const _Float16 yh = (_Float16)vy;
    const _Float16 xh2 = (_Float16)vx;
    FYhi[idx] = yh;
    FYlo[idx] = (_Float16)(vy - (float)yh);
    const int kaddr = ((col >> 3) << 9) + (n << 3) + (col & 7);
    FXk[kaddr] = xh2;
    FXk[8192 + kaddr] = (_Float16)(vx - (float)xh2);
  }
  if (tid == 0) ((float*)wsv)[16384] = expf(sc[4]) * DESCALE;
}

// ---------------------------------------------------------------------------
// fb_filt: one block (512 thr = 8 waves) per image; waves 0-3 process x,
// waves 4-7 process x_hat. ONE shared FX copy; 64 KB LDS -> 2 blocks/CU
// = 16 waves/CU; grid 1024 = 4 blocks/CU deep.
// LDS (halfs): [0,16384) FX hi/lo planes -> overwritten by S'_x hi/lo;
//              [16384,32768) S'_xh hi/lo planes.
// Phase 0: Z ks01 into regs; linear 32 KB coop copy of FX planes; barrier 1.
// Stage 1: Z ks23 issued (sched_barrier pinned); per ks: split Z in regs,
//   A-frags direct half8 ds_read (K-major), 24 MFMAs. Barrier 2.
// FY frags prefetched to regs; S' -> group's LDS planes (b16). Barrier 3.
// Stage 2: B-frags direct half8 ds_reads; 12 MFMAs/ks. Coalesced epilogue.
// 3-product f16 emulation: Ahi*Bhi + Ahi*Blo + Alo*Bhi (fp32 acc).
// ---------------------------------------------------------------------------
__device__ __forceinline__ void split8(const f32x4 z0, const f32x4 z1,
                                       float s, half8& hi, half8& lo) {
#pragma unroll
  for (int e = 0; e < 8; ++e) {
    const float q = (e < 4 ? z0[e] : z1[e - 4]) * s;
    const _Float16 hh = (_Float16)q;
    hi[e] = hh;
    lo[e] = (_Float16)(q - (float)hh);
  }
}

__global__ __launch_bounds__(512, 2) void fb_filt(
    const float* __restrict__ x, const float* __restrict__ xh,
    const void* __restrict__ wsv, float* __restrict__ out) {
  __shared__ __align__(16) _Float16 S_lds[4 * NN * AB];  // 64 KB

  const int tid = threadIdx.x;          // 0..511
  const int grp = tid >> 8;             // 0 = x, 1 = x_hat
  const int t8 = tid & 255;
  const int wv = t8 >> 6;               // 0..3 within group
  const int lane = tid & 63;
  const int l15 = lane & 15;
  const int h4 = lane >> 4;             // 0..3
  const int img = blockIdx.x;           // 1024 blocks, one per image
  const int sbase = grp << 14;          // group S' region (halfs)

  const float* __restrict__ Z = (grp ? xh : x) + (size_t)img * (AB * AB);
  const _Float16* __restrict__ FYhi = (const _Float16*)wsv + 2 * NN * AB;
  const _Float16* __restrict__ FYlo = FYhi + NN * AB;
  const float gamma_eff = ((const float*)wsv)[16384];

  // ---- Phase 0: Z ks01 batch + shared linear FX plane copy ----
  const float* __restrict__ zrow = Z + (32 * wv + l15) * AB + 8 * h4;
  f32x4 z[4][4];
#pragma unroll
  for (int ks = 0; ks < 2; ++ks) {
    const float* p0 = zrow + 32 * ks;
    const float* p1 = zrow + 16 * AB + 32 * ks;
    z[ks][0] = *(const f32x4*)p0;
    z[ks][1] = *(const f32x4*)(p0 + 4);
    z[ks][2] = *(const f32x4*)p1;
    z[ks][3] = *(const f32x4*)(p1 + 4);
  }
  {
    const u32x4* __restrict__ src = (const u32x4*)wsv;  // 2048 granules
    u32x4* __restrict__ dst = (u32x4*)S_lds;
#pragma unroll
    for (int c = 0; c < 4; ++c) dst[c * 512 + tid] = src[c * 512 + tid];
  }
  __syncthreads();  // barrier 1: FX planes resident

  // ---- issue Z ks23, pinned ahead of stage-1 compute ----
#pragma unroll
  for (int ks = 2; ks < 4; ++ks) {
    const float* p0 = zrow + 32 * ks;
    const float* p1 = zrow + 16 * AB + 32 * ks;
    z[ks][0] = *(const f32x4*)p0;
    z[ks][1] = *(const f32x4*)(p0 + 4);
    z[ks][2] = *(const f32x4*)p1;
    z[ks][3] = *(const f32x4*)(p1 + 4);
  }
  __builtin_amdgcn_sched_barrier(0);

  // ---- Stage 1: S'(64x128) = FXs @ Zs^T (per group) ----
  f32x4 acc[4][2];
#pragma unroll
  for (int mt = 0; mt < 4; ++mt)
#pragma unroll
    for (int j = 0; j < 2; ++j) acc[mt][j] = {0.f, 0.f, 0.f, 0.f};

#pragma unroll
  for (int ks = 0; ks < 4; ++ks) {
    half8 bhi[2], blo[2];
    split8(z[ks][0], z[ks][1], SFZ, bhi[0], blo[0]);
    split8(z[ks][2], z[ks][3], SFZ, bhi[1], blo[1]);
    const int gbase = ((4 * ks + h4) << 9);
#pragma unroll
    for (int mt = 0; mt < 4; ++mt) {
      const _Float16* ap = S_lds + gbase + ((16 * mt + l15) << 3);
      const half8 ahi = *(const half8*)ap;
      const half8 alo = *(const half8*)(ap + 8192);
#pragma unroll
      for (int j = 0; j < 2; ++j) {
        acc[mt][j] = __builtin_amdgcn_mfma_f32_16x16x32_f16(ahi, bhi[j], acc[mt][j], 0, 0, 0);
        acc[mt][j] = __builtin_amdgcn_mfma_f32_16x16x32_f16(ahi, blo[j], acc[mt][j], 0, 0, 0);
        acc[mt][j] = __builtin_amdgcn_mfma_f32_16x16x32_f16(alo, bhi[j], acc[mt][j], 0, 0, 0);
      }
    }
  }
  __syncthreads();  // barrier 2: all FX reads complete before overwrite

  // ---- prefetch FY frags into regs ----
  half8 fyh[4], fyl[4];
#pragma unroll
  for (int ks = 0; ks < 4; ++ks) {
    const int foff = (16 * wv + l15) * AB + 32 * ks + 8 * h4;
    fyh[ks] = *(const half8*)(FYhi + foff);
    fyl[ks] = *(const half8*)(FYlo + foff);
  }

  // ---- S' -> group's LDS planes (hi, lo) via b16 stores, K-major ----
#pragma unroll
  for (int mt = 0; mt < 4; ++mt) {
#pragma unroll
    for (int j = 0; j < 2; ++j) {
      // a = 32wv + 16j + l15 -> granule 4wv+2j+(l15>>3), elem l15&7
      const int abase = sbase + ((4 * wv + 2 * j + (l15 >> 3)) << 9) + (l15 & 7);
#pragma unroll
      for (int r = 0; r < 4; ++r) {
        const int row = 16 * mt + 4 * h4 + r;
        const float v = acc[mt][j][r];
        const _Float16 hh = (_Float16)v;
        const _Float16 ll = (_Float16)(v - (float)hh);
        S_lds[abase + (row << 3)] = hh;
        S_lds[8192 + abase + (row << 3)] = ll;
      }
    }
  }
  __syncthreads();  // barrier 3: S' resident

  // ---- Stage 2: out(64x64) = FYs @ S'^T (per group) ----
  f32x4 acc2[4];
#pragma unroll
  for (int mt = 0; mt < 4; ++mt) acc2[mt] = {0.f, 0.f, 0.f, 0.f};

#pragma unroll
  for (int ks = 0; ks < 4; ++ks) {
    const int gbase = sbase + ((4 * ks + h4) << 9);
#pragma unroll
    for (int mt = 0; mt < 4; ++mt) {
      const _Float16* bp = S_lds + gbase + ((16 * mt + l15) << 3);
      const half8 bh = *(const half8*)bp;
      const half8 bl = *(const half8*)(bp + 8192);
      acc2[mt] = __builtin_amdgcn_mfma_f32_16x16x32_f16(fyh[ks], bh, acc2[mt], 0, 0, 0);
      acc2[mt] = __builtin_amdgcn_mfma_f32_16x16x32_f16(fyh[ks], bl, acc2[mt], 0, 0, 0);
      acc2[mt] = __builtin_amdgcn_mfma_f32_16x16x32_f16(fyl[ks], bh, acc2[mt], 0, 0, 0);
    }
  }

  // ---- Epilogue: D[row = n = 16wv+4h4+r][col = m = 16mt+l15] ----
  float* __restrict__ ob = out + (size_t)img * 8192 + grp * 4096;
#pragma unroll
  for (int mt = 0; mt < 4; ++mt) {
#pragma unroll
    for (int r = 0; r < 4; ++r) {
      ob[(16 * wv + 4 * h4 + r) * 64 + 16 * mt + l15] = acc2[mt][r] * gamma_eff;
    }
  }
}

extern "C" void kernel_launch(void* const* d_in, const int* in_sizes, int n_in,
                              void* d_out, int out_size, void* d_ws, size_t ws_size,
                              hipStream_t stream) {
  const float* x = (const float*)d_in[0];
  const float* xh = (const float*)d_in[1];
  const float* h = (const float*)d_in[2];
  const float* Ww = (const float*)d_in[3];
  const float* Wb = (const float*)d_in[4];
  float* outp = (float*)d_out;

  fb_setup<<<1, 1024, 0, stream>>>(h, Ww, Wb, d_ws);
  fb_filt<<<1024, 512, 0, stream>>>(x, xh, (const void*)d_ws, outp);
}